// Round 8
// baseline (46.008 us; speedup 1.0000x reference)
//
#include <hip/hip_runtime.h>
#include <math.h>

// Problem: stimulus (32, 128*256) f32; H_real/H_imag (512, 256, 3) f32; out (32, 512) f32.
//   qf = fft2(q) over (128, 256); per (b,m): r = m%128;
//   acc = sum_w sum_d |ifft256(qf[b,r,:] * H[m,:,w])| ; out = acc/(256*256*3), thr 0.3.
//
// Forward k-axis FFT = DIF (natural in -> bitrev out); recon inverse = DIT (bitrev in ->
// natural out); pointwise multiply in bitrev space (H pre-permuted once). 256-pt FFTs
// register-resident: lane l owns {l, l+64, l+128, l+192}. Exchange plan per float2:
//   h=1,2 DPP quad_perm; h=4,8 __shfl_xor; h=16,32 permlane16/32_swap (VALU).
// Twiddle constants from ONE sincos via squaring chain: beta = exp(i pi lane/128);
//   stage-h coeff uses beta^(128/h) with sign (-1)^(lane&h) folded into A/B;
//   swap-form DIT stages need NO select: S32 = beta^4, S16 = beta^8.
// recon: 2 tasks (m, m+128) per wave share qv + constants. prep: 2 rows per wave.

#define TWO_PI 6.28318530717958647692f
#define PI_F   3.14159265358979323846f

#if __has_builtin(__builtin_amdgcn_permlane16_swap)
#define USE_PL16 1
#else
#define USE_PL16 0
#endif
#if __has_builtin(__builtin_amdgcn_permlane32_swap)
#define USE_PL32 1
#else
#define USE_PL32 0
#endif

typedef unsigned int uint2v __attribute__((ext_vector_type(2)));

__device__ inline float2 cmul(float2 a, float2 b) {
    return make_float2(a.x * b.x - a.y * b.y, a.x * b.y + a.y * b.x);
}
__device__ inline float2 cadd(float2 a, float2 b) { return make_float2(a.x + b.x, a.y + b.y); }
__device__ inline float2 csub(float2 a, float2 b) { return make_float2(a.x - b.x, a.y - b.y); }
__device__ inline float2 csq(float2 a) {  // a^2
    return make_float2(fmaf(a.x, a.x, -(a.y * a.y)), 2.0f * a.x * a.y);
}
// v' = A*v + B*o (complex, 8 fma)
__device__ inline float2 ab2(float2 A, float2 v, float2 B, float2 o) {
    return make_float2(A.x * v.x - A.y * v.y + B.x * o.x - B.y * o.y,
                       A.x * v.y + A.y * v.x + B.x * o.y + B.y * o.x);
}
// a + S*b (complex, 4 fma)
__device__ inline float2 cfma2(float2 S, float2 b, float2 a) {
    return make_float2(fmaf(S.x, b.x, fmaf(-S.y, b.y, a.x)),
                       fmaf(S.x, b.y, fmaf( S.y, b.x, a.y)));
}
__device__ inline float2 shfl_xor_c(float2 v, int mask) {
    return make_float2(__shfl_xor(v.x, mask, 64), __shfl_xor(v.y, mask, 64));
}

#define DPP_XOR1 0xB1  // quad_perm [1,0,3,2]
#define DPP_XOR2 0x4E  // quad_perm [2,3,0,1]
template <int CTRL>
__device__ inline float2 dpp_quad(float2 v) {
    return make_float2(
        __int_as_float(__builtin_amdgcn_update_dpp(__float_as_int(v.x), __float_as_int(v.x),
                                                   CTRL, 0xF, 0xF, false)),
        __int_as_float(__builtin_amdgcn_update_dpp(__float_as_int(v.y), __float_as_int(v.y),
                                                   CTRL, 0xF, 0xF, false)));
}

#if USE_PL16
// a = low-half element, b = high-half element (per 32-lane group at stride 16)
__device__ inline void swap16c(float2 v, float2& a, float2& b) {
    uint2v rx = __builtin_amdgcn_permlane16_swap(__float_as_uint(v.x), __float_as_uint(v.x), false, false);
    uint2v ry = __builtin_amdgcn_permlane16_swap(__float_as_uint(v.y), __float_as_uint(v.y), false, false);
    a = make_float2(__uint_as_float(rx[0]), __uint_as_float(ry[0]));
    b = make_float2(__uint_as_float(rx[1]), __uint_as_float(ry[1]));
}
#endif
#if USE_PL32
__device__ inline void swap32c(float2 v, float2& a, float2& b) {
    uint2v rx = __builtin_amdgcn_permlane32_swap(__float_as_uint(v.x), __float_as_uint(v.x), false, false);
    uint2v ry = __builtin_amdgcn_permlane32_swap(__float_as_uint(v.y), __float_as_uint(v.y), false, false);
    a = make_float2(__uint_as_float(rx[0]), __uint_as_float(ry[0]));
    b = make_float2(__uint_as_float(rx[1]), __uint_as_float(ry[1]));
}
#endif

// ---------------- Pass 1 (fused): row FFTs (2 rows/wave) + H transpose/bitrev ----
// blocks [0,512): 256-pt forward DIF FFT, wave g does rows 2g, 2g+1 (4096 rows).
// blocks [512,2048): Ht[m][w][p] = (Hr+i*Hi)[m][brev8(p)][w].
__global__ __launch_bounds__(256) void k_prep(const float* __restrict__ x,
                                              float2* __restrict__ y,
                                              const float* __restrict__ Hr,
                                              const float* __restrict__ Hi,
                                              float2* __restrict__ Ht) {
    if (blockIdx.x >= 512) {
        const int idx = (blockIdx.x - 512) * 256 + threadIdx.x;  // < 512*768
        const int m = idx / 768;
        const int rem = idx - m * 768;
        const int w = rem >> 8;
        const int p = rem & 255;
        const int k = __brev((unsigned)p) >> 24;
        const int src = (m * 256 + k) * 3 + w;
        Ht[idx] = make_float2(Hr[src], Hi[src]);
        return;
    }

    const int lane = threadIdx.x & 63;
    const int g    = blockIdx.x * 4 + (threadIdx.x >> 6);   // 0..2047
    const float fl = (float)lane;
    float sn, cs;

    // gamma = exp(-i pi lane/128); chain of squarings gives all DIF constants.
    __sincosf(-PI_F * fl * (1.0f / 128.0f), &sn, &cs);
    const float2 gam   = make_float2(cs, sn);
    const float2 w128_0 = gam;                                  // exp(-2pi i l/256)
    const float2 w128_1 = make_float2(gam.y, -gam.x);           // * exp(-i pi/2)
    const float2 w64f  = csq(gam);                              // exp(-2pi i l/128)
    const float2 g4    = csq(w64f);   // gamma^4  (h=32)
    const float2 g8    = csq(g4);     // gamma^8  (h=16)
    const float2 g16   = csq(g8);     // gamma^16 (h=8)
    const float2 g32   = csq(g16);    // gamma^32 (h=4)
    const float2 g64   = csq(g32);    // gamma^64 (h=2)
    const float2 one   = make_float2(1.0f, 0.0f);
#if USE_PL32
    const float2 P32 = (lane & 32) ? make_float2(-g4.x, -g4.y) : one;
    const float2 Q32 = (lane & 32) ? g4 : one;
#else
    const float2 A32f = (lane & 32) ? g4 : one;
    const float2 B32f = (lane & 32) ? make_float2(-g4.x, -g4.y) : one;
#endif
#if USE_PL16
    const float2 P16 = (lane & 16) ? make_float2(-g8.x, -g8.y) : one;
    const float2 Q16 = (lane & 16) ? g8 : one;
#else
    const float2 A16f = (lane & 16) ? g8 : one;
    const float2 B16f = (lane & 16) ? make_float2(-g8.x, -g8.y) : one;
#endif
    const float2 A8f = (lane & 8) ? g16 : one;
    const float2 B8f = (lane & 8) ? make_float2(-g16.x, -g16.y) : one;
    const float2 A4f = (lane & 4) ? g32 : one;
    const float2 B4f = (lane & 4) ? make_float2(-g32.x, -g32.y) : one;
    const float2 A2f = (lane & 2) ? g64 : one;
    const float2 B2f = (lane & 2) ? make_float2(-g64.x, -g64.y) : one;
    const float sgn1 = (lane & 1) ? -1.0f : 1.0f;

    const float* xbase = x + (size_t)(2 * g) * 256;
    float2*      ybase = y + (size_t)(2 * g) * 256;

#pragma unroll
    for (int tt = 0; tt < 2; ++tt) {
        const float* xr = xbase + tt * 256;
        float2 v[4];
        v[0] = make_float2(xr[lane],       0.0f);
        v[1] = make_float2(xr[64 + lane],  0.0f);
        v[2] = make_float2(xr[128 + lane], 0.0f);
        v[3] = make_float2(xr[192 + lane], 0.0f);

        // in-register DIF h=128, h=64
        { float2 a = v[0], bq = v[2]; v[0] = cadd(a, bq); v[2] = cmul(csub(a, bq), w128_0); }
        { float2 a = v[1], bq = v[3]; v[1] = cadd(a, bq); v[3] = cmul(csub(a, bq), w128_1); }
        { float2 a = v[0], bq = v[1]; v[0] = cadd(a, bq); v[1] = cmul(csub(a, bq), w64f); }
        { float2 a = v[2], bq = v[3]; v[2] = cadd(a, bq); v[3] = cmul(csub(a, bq), w64f); }

        // h=32
#pragma unroll
        for (int j = 0; j < 4; ++j) {
#if USE_PL32
            float2 a, bb; swap32c(v[j], a, bb);
            v[j] = ab2(P32, a, Q32, bb);
#else
            const float2 o = shfl_xor_c(v[j], 32);
            v[j] = ab2(A32f, v[j], B32f, o);
#endif
        }
        // h=16
#pragma unroll
        for (int j = 0; j < 4; ++j) {
#if USE_PL16
            float2 a, bb; swap16c(v[j], a, bb);
            v[j] = ab2(P16, a, Q16, bb);
#else
            const float2 o = shfl_xor_c(v[j], 16);
            v[j] = ab2(A16f, v[j], B16f, o);
#endif
        }
        // h=8, h=4 (shfl)
#pragma unroll
        for (int j = 0; j < 4; ++j) {
            const float2 o = shfl_xor_c(v[j], 8);
            v[j] = ab2(A8f, v[j], B8f, o);
        }
#pragma unroll
        for (int j = 0; j < 4; ++j) {
            const float2 o = shfl_xor_c(v[j], 4);
            v[j] = ab2(A4f, v[j], B4f, o);
        }
        // h=2 (DPP)
#pragma unroll
        for (int j = 0; j < 4; ++j) {
            const float2 o = dpp_quad<DPP_XOR2>(v[j]);
            v[j] = ab2(A2f, v[j], B2f, o);
        }
        // h=1 (DPP, W==1)
#pragma unroll
        for (int j = 0; j < 4; ++j) {
            const float2 o = dpp_quad<DPP_XOR1>(v[j]);
            v[j] = make_float2(fmaf(sgn1, v[j].x, o.x), fmaf(sgn1, v[j].y, o.y));
        }

        float2* yr = ybase + tt * 256;
#pragma unroll
        for (int j = 0; j < 4; ++j) yr[j * 64 + lane] = v[j];
    }
}

// ---------------- Pass 2: 128-pt forward DIT FFT along r, in place (LDS) ---------
__global__ __launch_bounds__(256) void k_fft_cols(float2* __restrict__ y) {
    __shared__ float2 sm[128][17];
    __shared__ float2 tw[64];
    const int tid = threadIdx.x;

    if (tid < 64) {
        float sn, cs;
        __sincosf(-TWO_PI * (float)tid * (1.0f / 128.0f), &sn, &cs);
        tw[tid] = make_float2(cs, sn);
    }

    const int b  = blockIdx.x >> 4;
    const int d0 = (blockIdx.x & 15) << 4;
    const int c  = tid & 15;
    const int r0 = tid >> 4;  // 0..15
    const size_t base = ((size_t)b * 128) * 256 + (size_t)d0 + (size_t)c;

#pragma unroll
    for (int r = r0; r < 128; r += 16) {
        sm[__brev((unsigned)r) >> 25][c] = y[base + (size_t)r * 256];
    }
    __syncthreads();

#pragma unroll
    for (int st = 0; st < 7; ++st) {
        const int half = 1 << st;
#pragma unroll
        for (int k = 0; k < 4; ++k) {
            const int idx = tid + (k << 8);
            const int cc  = idx & 15;
            const int j   = idx >> 4;
            const int pos = j & (half - 1);
            const int i0  = (j << 1) - pos;
            const int i1  = i0 + half;
            const float2 w  = tw[pos << (6 - st)];
            const float2 a  = sm[i0][cc];
            const float2 bv = cmul(sm[i1][cc], w);
            sm[i0][cc] = cadd(a, bv);
            sm[i1][cc] = csub(a, bv);
        }
        __syncthreads();
    }

#pragma unroll
    for (int r = r0; r < 128; r += 16) {
        y[base + (size_t)r * 256] = sm[r][c];
    }
}

// ---------------- Pass 3: 2 tasks/wave (m, m+128 share qrow), 3x iFFT each -------
__global__ __launch_bounds__(256) void k_recon(const float2* __restrict__ qf,
                                               const float2* __restrict__ Ht,
                                               float* __restrict__ out) {
    const int lane = threadIdx.x & 63;
    const int t    = blockIdx.x * 4 + (threadIdx.x >> 6);   // 0..8191
    const int b    = t >> 8;
    const int u    = t & 255;
    const int r    = u & 127;
    const int mb   = r + ((u >> 7) << 8);   // r or r+256; tasks mb, mb+128

    // issue q loads early; constants compute under the load latency
    const float2* q = qf + ((size_t)(b * 128 + r)) * 256;
    float2 qv[4];
#pragma unroll
    for (int j = 0; j < 4; ++j) qv[j] = q[j * 64 + lane];

    const float fl = (float)lane;
    float sn, cs;
    // beta = exp(+i pi lane/128); chain gives all DIT constants.
    __sincosf(PI_F * fl * (1.0f / 128.0f), &sn, &cs);
    const float2 wi0 = make_float2(cs, sn);   // beta  (h=128 twiddle)
    const float2 w64 = csq(wi0);              // beta^2 (h=64)
    const float2 S32 = csq(w64);              // beta^4  -> h=32 swap, no select
    const float2 S16 = csq(S32);              // beta^8  -> h=16 swap, no select
    const float2 b16 = csq(S16);              // beta^16 (h=8)
    const float2 b32 = csq(b16);              // beta^32 (h=4)
    const float2 b64 = csq(b32);              // beta^64 (h=2)
    const float2 one = make_float2(1.0f, 0.0f);
    const float2 A8 = (lane & 8) ? b16 : one, B8 = (lane & 8) ? one : b16;
    const float2 A4 = (lane & 4) ? b32 : one, B4 = (lane & 4) ? one : b32;
    const float2 A2 = (lane & 2) ? b64 : one, B2 = (lane & 2) ? one : b64;
    const float sgn1 = (lane & 1) ? -1.0f : 1.0f;
    const float2 wi1 = make_float2(-wi0.y, wi0.x);
#if !USE_PL16
    const float2 A16 = (lane & 16) ? S16 : one, B16 = (lane & 16) ? one : S16;
#endif
#if !USE_PL32
    const float2 A32 = (lane & 32) ? S32 : one, B32 = (lane & 32) ? one : S32;
#endif

#pragma unroll
    for (int tt = 0; tt < 2; ++tt) {
        const int m = mb + tt * 128;
        const float2* hp = Ht + (size_t)m * 768;

        float2 v[3][4];
#pragma unroll
        for (int w = 0; w < 3; ++w)
#pragma unroll
            for (int j = 0; j < 4; ++j)
                v[w][j] = cmul(qv[j], hp[w * 256 + j * 64 + lane]);

        // h=1 (DPP, W==1)
#pragma unroll
        for (int w = 0; w < 3; ++w)
#pragma unroll
            for (int j = 0; j < 4; ++j) {
                const float2 o = dpp_quad<DPP_XOR1>(v[w][j]);
                v[w][j] = make_float2(fmaf(sgn1, v[w][j].x, o.x), fmaf(sgn1, v[w][j].y, o.y));
            }
        // h=2 (DPP)
#pragma unroll
        for (int w = 0; w < 3; ++w)
#pragma unroll
            for (int j = 0; j < 4; ++j) {
                const float2 o = dpp_quad<DPP_XOR2>(v[w][j]);
                v[w][j] = ab2(A2, v[w][j], B2, o);
            }
        // h=4 (shfl)
#pragma unroll
        for (int w = 0; w < 3; ++w)
#pragma unroll
            for (int j = 0; j < 4; ++j) {
                const float2 o = shfl_xor_c(v[w][j], 4);
                v[w][j] = ab2(A4, v[w][j], B4, o);
            }
        // h=8 (shfl)
#pragma unroll
        for (int w = 0; w < 3; ++w)
#pragma unroll
            for (int j = 0; j < 4; ++j) {
                const float2 o = shfl_xor_c(v[w][j], 8);
                v[w][j] = ab2(A8, v[w][j], B8, o);
            }
        // h=16 (swap): v' = a + S16*b
#pragma unroll
        for (int w = 0; w < 3; ++w)
#pragma unroll
            for (int j = 0; j < 4; ++j) {
#if USE_PL16
                float2 a, bb; swap16c(v[w][j], a, bb);
                v[w][j] = cfma2(S16, bb, a);
#else
                const float2 o = shfl_xor_c(v[w][j], 16);
                v[w][j] = ab2(A16, v[w][j], B16, o);
#endif
            }
        // h=32 (swap): v' = a + S32*b
#pragma unroll
        for (int w = 0; w < 3; ++w)
#pragma unroll
            for (int j = 0; j < 4; ++j) {
#if USE_PL32
                float2 a, bb; swap32c(v[w][j], a, bb);
                v[w][j] = cfma2(S32, bb, a);
#else
                const float2 o = shfl_xor_c(v[w][j], 32);
                v[w][j] = ab2(A32, v[w][j], B32, o);
#endif
            }
        // in-register h=64, h=128
#pragma unroll
        for (int w = 0; w < 3; ++w) {
            float2 tv = cmul(w64, v[w][1]);
            float2 a = v[w][0];
            v[w][0] = cadd(a, tv); v[w][1] = csub(a, tv);
            tv = cmul(w64, v[w][3]);
            a = v[w][2];
            v[w][2] = cadd(a, tv); v[w][3] = csub(a, tv);
            tv = cmul(wi0, v[w][2]);
            a = v[w][0];
            v[w][0] = cadd(a, tv); v[w][2] = csub(a, tv);
            tv = cmul(wi1, v[w][3]);
            a = v[w][1];
            v[w][1] = cadd(a, tv); v[w][3] = csub(a, tv);
        }

        float acc = 0.0f;
#pragma unroll
        for (int w = 0; w < 3; ++w)
#pragma unroll
            for (int j = 0; j < 4; ++j)
                acc += __builtin_amdgcn_sqrtf(fmaf(v[w][j].x, v[w][j].x, v[w][j].y * v[w][j].y));

#pragma unroll
        for (int off = 32; off > 0; off >>= 1) acc += __shfl_xor(acc, off, 64);

        if (lane == 0) {
            const float focused = acc * (1.0f / (256.0f * 256.0f * 3.0f));
            out[b * 512 + m] = (focused > 0.3f) ? focused : 0.0f;
        }
    }
}

extern "C" void kernel_launch(void* const* d_in, const int* in_sizes, int n_in,
                              void* d_out, int out_size, void* d_ws, size_t ws_size,
                              hipStream_t stream) {
    (void)in_sizes; (void)n_in; (void)out_size; (void)ws_size;
    const float* stim = (const float*)d_in[0];   // (32, 32768)
    const float* Hr   = (const float*)d_in[1];   // (512, 256, 3)
    const float* Hi   = (const float*)d_in[2];   // (512, 256, 3)
    float* out = (float*)d_out;                  // (32, 512)

    float2* y  = (float2*)d_ws;                                                     // 8 MB
    float2* Ht = (float2*)((char*)d_ws + (size_t)32 * 128 * 256 * sizeof(float2));  // 3 MB

    k_prep<<<512 + 1536, 256, 0, stream>>>(stim, y, Hr, Hi, Ht);
    k_fft_cols<<<32 * 16, 256, 0, stream>>>(y);
    k_recon<<<8192 / 4, 256, 0, stream>>>(y, Ht, out);
}

// Round 9
// 44.150 us; speedup vs baseline: 1.0421x; 1.0421x over previous
//
#include <hip/hip_runtime.h>
#include <math.h>

// Problem: stimulus (32, 128*256) f32; H_real/H_imag (512, 256, 3) f32; out (32, 512) f32.
//   qf = fft2(q) over (128, 256); per (b,m): r = m%128;
//   acc = sum_w sum_d |ifft256(qf[b,r,:] * H[m,:,w])| ; out = acc/(256*256*3), thr 0.3.
//
// Forward k-axis FFT = DIF (natural in -> bitrev out); recon inverse = DIT (bitrev in ->
// natural out); pointwise multiply in bitrev space (H pre-permuted once). 256-pt FFTs
// register-resident: lane l owns {l, l+64, l+128, l+192}. Exchange plan per complex:
//   h=1,2 DPP quad_perm; h=4,8 __shfl_xor; h=16,32 permlane16/32_swap (VALU).
// Twiddles from ONE sincos via squaring chain (beta = exp(i pi lane/128)).
// Complex numbers are ext_vector float2 with VECTOR arithmetic -> v_pk_fma_f32/v_pk_add
// (packed fp32: scalar v_fma tops at ~103 TF, packed reaches 157 TF).
// recon: 1 task/wave (16384 waves) -- TLP is what hides shuffle latency (round-8 lesson).

#define TWO_PI 6.28318530717958647692f
#define PI_F   3.14159265358979323846f

#if __has_builtin(__builtin_amdgcn_permlane16_swap)
#define USE_PL16 1
#else
#define USE_PL16 0
#endif
#if __has_builtin(__builtin_amdgcn_permlane32_swap)
#define USE_PL32 1
#else
#define USE_PL32 0
#endif

typedef float f2 __attribute__((ext_vector_type(2)));
typedef unsigned int uint2v __attribute__((ext_vector_type(2)));

__device__ inline f2 mkf2(float x, float y) { f2 r; r[0] = x; r[1] = y; return r; }

// complex mul: (a.x*b.x - a.y*b.y, a.x*b.y + a.y*b.x) = a.xx*b + (-a.y,a.y)*b.yx
__device__ inline f2 cmul(f2 a, f2 b) {
    const f2 axx = __builtin_shufflevector(a, a, 0, 0);
    const f2 ayn = mkf2(-a[1], a[1]);
    const f2 byx = __builtin_shufflevector(b, b, 1, 0);
    return axx * b + ayn * byx;
}
__device__ inline f2 csq(f2 a) { return cmul(a, a); }
// v' = A*v + B*o  (4 packed fma)
__device__ inline f2 ab2(f2 A, f2 v, f2 B, f2 o) {
    const f2 Axx = __builtin_shufflevector(A, A, 0, 0);
    const f2 Ayn = mkf2(-A[1], A[1]);
    const f2 Bxx = __builtin_shufflevector(B, B, 0, 0);
    const f2 Byn = mkf2(-B[1], B[1]);
    const f2 vyx = __builtin_shufflevector(v, v, 1, 0);
    const f2 oyx = __builtin_shufflevector(o, o, 1, 0);
    return Axx * v + Ayn * vyx + Bxx * o + Byn * oyx;
}
// a + S*b  (2 packed fma)
__device__ inline f2 cfma2(f2 S, f2 b, f2 a) {
    const f2 Sxx = __builtin_shufflevector(S, S, 0, 0);
    const f2 Syn = mkf2(-S[1], S[1]);
    const f2 byx = __builtin_shufflevector(b, b, 1, 0);
    return Sxx * b + (Syn * byx + a);
}
__device__ inline f2 shfl_xor_c(f2 v, int mask) {
    return mkf2(__shfl_xor(v[0], mask, 64), __shfl_xor(v[1], mask, 64));
}

#define DPP_XOR1 0xB1  // quad_perm [1,0,3,2]
#define DPP_XOR2 0x4E  // quad_perm [2,3,0,1]
template <int CTRL>
__device__ inline f2 dpp_quad(f2 v) {
    return mkf2(
        __int_as_float(__builtin_amdgcn_update_dpp(__float_as_int(v[0]), __float_as_int(v[0]),
                                                   CTRL, 0xF, 0xF, false)),
        __int_as_float(__builtin_amdgcn_update_dpp(__float_as_int(v[1]), __float_as_int(v[1]),
                                                   CTRL, 0xF, 0xF, false)));
}

#if USE_PL16
__device__ inline void swap16c(f2 v, f2& a, f2& b) {
    uint2v rx = __builtin_amdgcn_permlane16_swap(__float_as_uint(v[0]), __float_as_uint(v[0]), false, false);
    uint2v ry = __builtin_amdgcn_permlane16_swap(__float_as_uint(v[1]), __float_as_uint(v[1]), false, false);
    a = mkf2(__uint_as_float(rx[0]), __uint_as_float(ry[0]));
    b = mkf2(__uint_as_float(rx[1]), __uint_as_float(ry[1]));
}
#endif
#if USE_PL32
__device__ inline void swap32c(f2 v, f2& a, f2& b) {
    uint2v rx = __builtin_amdgcn_permlane32_swap(__float_as_uint(v[0]), __float_as_uint(v[0]), false, false);
    uint2v ry = __builtin_amdgcn_permlane32_swap(__float_as_uint(v[1]), __float_as_uint(v[1]), false, false);
    a = mkf2(__uint_as_float(rx[0]), __uint_as_float(ry[0]));
    b = mkf2(__uint_as_float(rx[1]), __uint_as_float(ry[1]));
}
#endif

// ---------------- Pass 1 (fused): row FFTs (1 row/wave) + H transpose/bitrev -----
// blocks [0,1024): 256-pt forward DIF FFT per row (4096 rows).
// blocks [1024,2560): Ht[m][w][p] = (Hr+i*Hi)[m][brev8(p)][w].
__global__ __launch_bounds__(256) void k_prep(const float* __restrict__ x,
                                              f2* __restrict__ y,
                                              const float* __restrict__ Hr,
                                              const float* __restrict__ Hi,
                                              f2* __restrict__ Ht) {
    if (blockIdx.x >= 1024) {
        const int idx = (blockIdx.x - 1024) * 256 + threadIdx.x;  // < 512*768
        const int m = idx / 768;
        const int rem = idx - m * 768;
        const int w = rem >> 8;
        const int p = rem & 255;
        const int k = __brev((unsigned)p) >> 24;
        const int src = (m * 256 + k) * 3 + w;
        Ht[idx] = mkf2(Hr[src], Hi[src]);
        return;
    }

    const int lane = threadIdx.x & 63;
    const int wid  = blockIdx.x * 4 + (threadIdx.x >> 6);   // row id 0..4095
    float sn, cs;

    // gamma = exp(-i pi lane/128); squaring chain gives all DIF constants.
    __sincosf(-PI_F * (float)lane * (1.0f / 128.0f), &sn, &cs);
    const f2 gam    = mkf2(cs, sn);
    const f2 w128_0 = gam;                       // exp(-2pi i l/256)
    const f2 w128_1 = mkf2(gam[1], -gam[0]);     // * exp(-i pi/2)
    const f2 w64f = csq(gam);                    // exp(-2pi i l/128)
    const f2 g4   = csq(w64f);   // gamma^4  (h=32)
    const f2 g8   = csq(g4);     // gamma^8  (h=16)
    const f2 g16  = csq(g8);     // gamma^16 (h=8)
    const f2 g32  = csq(g16);    // gamma^32 (h=4)
    const f2 g64  = csq(g32);    // gamma^64 (h=2)
    const f2 one  = mkf2(1.0f, 0.0f);
#if USE_PL32
    const f2 P32 = (lane & 32) ? mkf2(-g4[0], -g4[1]) : one;
    const f2 Q32 = (lane & 32) ? g4 : one;
#else
    const f2 A32f = (lane & 32) ? g4 : one;
    const f2 B32f = (lane & 32) ? mkf2(-g4[0], -g4[1]) : one;
#endif
#if USE_PL16
    const f2 P16 = (lane & 16) ? mkf2(-g8[0], -g8[1]) : one;
    const f2 Q16 = (lane & 16) ? g8 : one;
#else
    const f2 A16f = (lane & 16) ? g8 : one;
    const f2 B16f = (lane & 16) ? mkf2(-g8[0], -g8[1]) : one;
#endif
    const f2 A8f = (lane & 8) ? g16 : one;
    const f2 B8f = (lane & 8) ? mkf2(-g16[0], -g16[1]) : one;
    const f2 A4f = (lane & 4) ? g32 : one;
    const f2 B4f = (lane & 4) ? mkf2(-g32[0], -g32[1]) : one;
    const f2 A2f = (lane & 2) ? g64 : one;
    const f2 B2f = (lane & 2) ? mkf2(-g64[0], -g64[1]) : one;
    const f2 sg1 = (lane & 1) ? mkf2(-1.0f, -1.0f) : mkf2(1.0f, 1.0f);

    const float* xr = x + (size_t)wid * 256;
    f2 v[4];
    v[0] = mkf2(xr[lane],       0.0f);
    v[1] = mkf2(xr[64 + lane],  0.0f);
    v[2] = mkf2(xr[128 + lane], 0.0f);
    v[3] = mkf2(xr[192 + lane], 0.0f);

    // in-register DIF h=128, h=64
    { f2 a = v[0], bq = v[2]; v[0] = a + bq; v[2] = cmul(a - bq, w128_0); }
    { f2 a = v[1], bq = v[3]; v[1] = a + bq; v[3] = cmul(a - bq, w128_1); }
    { f2 a = v[0], bq = v[1]; v[0] = a + bq; v[1] = cmul(a - bq, w64f); }
    { f2 a = v[2], bq = v[3]; v[2] = a + bq; v[3] = cmul(a - bq, w64f); }

    // h=32
#pragma unroll
    for (int j = 0; j < 4; ++j) {
#if USE_PL32
        f2 a, bb; swap32c(v[j], a, bb);
        v[j] = ab2(P32, a, Q32, bb);
#else
        const f2 o = shfl_xor_c(v[j], 32);
        v[j] = ab2(A32f, v[j], B32f, o);
#endif
    }
    // h=16
#pragma unroll
    for (int j = 0; j < 4; ++j) {
#if USE_PL16
        f2 a, bb; swap16c(v[j], a, bb);
        v[j] = ab2(P16, a, Q16, bb);
#else
        const f2 o = shfl_xor_c(v[j], 16);
        v[j] = ab2(A16f, v[j], B16f, o);
#endif
    }
    // h=8, h=4 (shfl)
#pragma unroll
    for (int j = 0; j < 4; ++j) {
        const f2 o = shfl_xor_c(v[j], 8);
        v[j] = ab2(A8f, v[j], B8f, o);
    }
#pragma unroll
    for (int j = 0; j < 4; ++j) {
        const f2 o = shfl_xor_c(v[j], 4);
        v[j] = ab2(A4f, v[j], B4f, o);
    }
    // h=2 (DPP)
#pragma unroll
    for (int j = 0; j < 4; ++j) {
        const f2 o = dpp_quad<DPP_XOR2>(v[j]);
        v[j] = ab2(A2f, v[j], B2f, o);
    }
    // h=1 (DPP, W==1): v' = sgn*v + o  (1 packed fma)
#pragma unroll
    for (int j = 0; j < 4; ++j) {
        const f2 o = dpp_quad<DPP_XOR1>(v[j]);
        v[j] = sg1 * v[j] + o;
    }

    f2* yr = y + (size_t)wid * 256;
#pragma unroll
    for (int j = 0; j < 4; ++j) yr[j * 64 + lane] = v[j];
}

// ---------------- Pass 2: 128-pt forward DIT FFT along r, in place (LDS) ---------
__global__ __launch_bounds__(256) void k_fft_cols(f2* __restrict__ y) {
    __shared__ f2 sm[128][17];
    __shared__ f2 tw[64];
    const int tid = threadIdx.x;

    if (tid < 64) {
        float sn, cs;
        __sincosf(-TWO_PI * (float)tid * (1.0f / 128.0f), &sn, &cs);
        tw[tid] = mkf2(cs, sn);
    }

    const int b  = blockIdx.x >> 4;
    const int d0 = (blockIdx.x & 15) << 4;
    const int c  = tid & 15;
    const int r0 = tid >> 4;  // 0..15
    const size_t base = ((size_t)b * 128) * 256 + (size_t)d0 + (size_t)c;

#pragma unroll
    for (int r = r0; r < 128; r += 16) {
        sm[__brev((unsigned)r) >> 25][c] = y[base + (size_t)r * 256];
    }
    __syncthreads();

#pragma unroll
    for (int st = 0; st < 7; ++st) {
        const int half = 1 << st;
#pragma unroll
        for (int k = 0; k < 4; ++k) {
            const int idx = tid + (k << 8);
            const int cc  = idx & 15;
            const int j   = idx >> 4;
            const int pos = j & (half - 1);
            const int i0  = (j << 1) - pos;
            const int i1  = i0 + half;
            const f2 w  = tw[pos << (6 - st)];
            const f2 a  = sm[i0][cc];
            const f2 bv = cmul(sm[i1][cc], w);
            sm[i0][cc] = a + bv;
            sm[i1][cc] = a - bv;
        }
        __syncthreads();
    }

#pragma unroll
    for (int r = r0; r < 128; r += 16) {
        y[base + (size_t)r * 256] = sm[r][c];
    }
}

// ---------------- Pass 3: per (b,m): 3x inverse 256-pt DIT FFT, 1 task/wave ------
__global__ __launch_bounds__(256) void k_recon(const f2* __restrict__ qf,
                                               const f2* __restrict__ Ht,
                                               float* __restrict__ out) {
    const int lane = threadIdx.x & 63;
    const int task = blockIdx.x * 4 + (threadIdx.x >> 6);  // b*512 + m
    const int b = task >> 9;
    const int m = task & 511;
    const int r = m & 127;

    // issue q loads early; constants compute under the load latency
    const f2* q = qf + ((size_t)(b * 128 + r)) * 256;
    f2 qv[4];
#pragma unroll
    for (int j = 0; j < 4; ++j) qv[j] = q[j * 64 + lane];

    float sn, cs;
    // beta = exp(+i pi lane/128); squaring chain gives all DIT constants.
    __sincosf(PI_F * (float)lane * (1.0f / 128.0f), &sn, &cs);
    const f2 wi0 = mkf2(cs, sn);   // beta    (h=128 twiddle)
    const f2 w64 = csq(wi0);       // beta^2  (h=64)
    const f2 S32 = csq(w64);       // beta^4  -> h=32 swap, no select
    const f2 S16 = csq(S32);       // beta^8  -> h=16 swap, no select
    const f2 b16 = csq(S16);       // beta^16 (h=8)
    const f2 b32 = csq(b16);       // beta^32 (h=4)
    const f2 b64 = csq(b32);       // beta^64 (h=2)
    const f2 one = mkf2(1.0f, 0.0f);
    const f2 A8 = (lane & 8) ? b16 : one, B8 = (lane & 8) ? one : b16;
    const f2 A4 = (lane & 4) ? b32 : one, B4 = (lane & 4) ? one : b32;
    const f2 A2 = (lane & 2) ? b64 : one, B2 = (lane & 2) ? one : b64;
    const f2 sg1 = (lane & 1) ? mkf2(-1.0f, -1.0f) : mkf2(1.0f, 1.0f);
    const f2 wi1 = mkf2(-wi0[1], wi0[0]);
#if !USE_PL16
    const f2 A16 = (lane & 16) ? S16 : one, B16 = (lane & 16) ? one : S16;
#endif
#if !USE_PL32
    const f2 A32 = (lane & 32) ? S32 : one, B32 = (lane & 32) ? one : S32;
#endif

    const f2* hp = Ht + (size_t)m * 768;
    f2 v[3][4];
#pragma unroll
    for (int w = 0; w < 3; ++w)
#pragma unroll
        for (int j = 0; j < 4; ++j)
            v[w][j] = cmul(qv[j], hp[w * 256 + j * 64 + lane]);

    // h=1 (DPP, W==1): v' = sgn*v + o
#pragma unroll
    for (int w = 0; w < 3; ++w)
#pragma unroll
        for (int j = 0; j < 4; ++j) {
            const f2 o = dpp_quad<DPP_XOR1>(v[w][j]);
            v[w][j] = sg1 * v[w][j] + o;
        }
    // h=2 (DPP)
#pragma unroll
    for (int w = 0; w < 3; ++w)
#pragma unroll
        for (int j = 0; j < 4; ++j) {
            const f2 o = dpp_quad<DPP_XOR2>(v[w][j]);
            v[w][j] = ab2(A2, v[w][j], B2, o);
        }
    // h=4 (shfl)
#pragma unroll
    for (int w = 0; w < 3; ++w)
#pragma unroll
        for (int j = 0; j < 4; ++j) {
            const f2 o = shfl_xor_c(v[w][j], 4);
            v[w][j] = ab2(A4, v[w][j], B4, o);
        }
    // h=8 (shfl)
#pragma unroll
    for (int w = 0; w < 3; ++w)
#pragma unroll
        for (int j = 0; j < 4; ++j) {
            const f2 o = shfl_xor_c(v[w][j], 8);
            v[w][j] = ab2(A8, v[w][j], B8, o);
        }
    // h=16 (swap): v' = a + S16*b
#pragma unroll
    for (int w = 0; w < 3; ++w)
#pragma unroll
        for (int j = 0; j < 4; ++j) {
#if USE_PL16
            f2 a, bb; swap16c(v[w][j], a, bb);
            v[w][j] = cfma2(S16, bb, a);
#else
            const f2 o = shfl_xor_c(v[w][j], 16);
            v[w][j] = ab2(A16, v[w][j], B16, o);
#endif
        }
    // h=32 (swap): v' = a + S32*b
#pragma unroll
    for (int w = 0; w < 3; ++w)
#pragma unroll
        for (int j = 0; j < 4; ++j) {
#if USE_PL32
            f2 a, bb; swap32c(v[w][j], a, bb);
            v[w][j] = cfma2(S32, bb, a);
#else
            const f2 o = shfl_xor_c(v[w][j], 32);
            v[w][j] = ab2(A32, v[w][j], B32, o);
#endif
        }
    // in-register h=64, h=128
#pragma unroll
    for (int w = 0; w < 3; ++w) {
        f2 tv = cmul(w64, v[w][1]);
        f2 a = v[w][0];
        v[w][0] = a + tv; v[w][1] = a - tv;
        tv = cmul(w64, v[w][3]);
        a = v[w][2];
        v[w][2] = a + tv; v[w][3] = a - tv;
        tv = cmul(wi0, v[w][2]);
        a = v[w][0];
        v[w][0] = a + tv; v[w][2] = a - tv;
        tv = cmul(wi1, v[w][3]);
        a = v[w][1];
        v[w][1] = a + tv; v[w][3] = a - tv;
    }

    float acc = 0.0f;
#pragma unroll
    for (int w = 0; w < 3; ++w)
#pragma unroll
        for (int j = 0; j < 4; ++j) {
            const f2 sq = v[w][j] * v[w][j];            // packed mul
            acc += __builtin_amdgcn_sqrtf(sq[0] + sq[1]);
        }

#pragma unroll
    for (int off = 32; off > 0; off >>= 1) acc += __shfl_xor(acc, off, 64);

    if (lane == 0) {
        const float focused = acc * (1.0f / (256.0f * 256.0f * 3.0f));
        out[task] = (focused > 0.3f) ? focused : 0.0f;
    }
}

extern "C" void kernel_launch(void* const* d_in, const int* in_sizes, int n_in,
                              void* d_out, int out_size, void* d_ws, size_t ws_size,
                              hipStream_t stream) {
    (void)in_sizes; (void)n_in; (void)out_size; (void)ws_size;
    const float* stim = (const float*)d_in[0];   // (32, 32768)
    const float* Hr   = (const float*)d_in[1];   // (512, 256, 3)
    const float* Hi   = (const float*)d_in[2];   // (512, 256, 3)
    float* out = (float*)d_out;                  // (32, 512)

    f2* y  = (f2*)d_ws;                                                  // 8 MB
    f2* Ht = (f2*)((char*)d_ws + (size_t)32 * 128 * 256 * sizeof(f2));   // 3 MB

    k_prep<<<1024 + 1536, 256, 0, stream>>>(stim, y, Hr, Hi, Ht);
    k_fft_cols<<<32 * 16, 256, 0, stream>>>(y);
    k_recon<<<16384 / 4, 256, 0, stream>>>(y, Ht, out);
}